// Round 1
// baseline (170.332 us; speedup 1.0000x reference)
//
#include <hip/hip_runtime.h>

// ---------------- types / helpers ----------------
typedef __attribute__((ext_vector_type(8))) __bf16 bf16x8;
typedef __attribute__((ext_vector_type(8))) short short8;
typedef __attribute__((ext_vector_type(4))) float f32x4;

static __device__ __forceinline__ unsigned short f2bf(float f) {
    unsigned u = __float_as_uint(f);
    u += 0x7FFFu + ((u >> 16) & 1u);
    return (unsigned short)(u >> 16);
}
static __device__ __forceinline__ bf16x8 as_bf16x8(short8 v) {
    return __builtin_bit_cast(bf16x8, v);
}

// problem sizes
#define NB 8
#define NS 5
#define NQ 15
// ws layout (in floats)
#define A_ROWS (NB*NS*16)          // 640
#define B_ROWS (NB*NQ*16)          // 1920
#define A_OFF_F 0
#define B_OFF_F (A_ROWS*256)                   // 163840
#define XF_OFF_F (B_OFF_F + B_ROWS*256)        // 655360
#define WF_OFF_BYTES ((XF_OFF_F + 600*256)*4)  // 3235840 (16B aligned)

// ---------------- kernel 1: precompute A (sup@W1a + b1) and B (qry@W1b) ----------------
// grid = 640 + 1920 blocks, 256 threads. One block = one row of 258-dim input.
__global__ void k1_rows(const float* __restrict__ sup, const float* __restrict__ qry,
                        const float* __restrict__ gw1, const float* __restrict__ gb1,
                        float* __restrict__ ws) {
    __shared__ float x[258];
    int r = blockIdx.x;
    int t = threadIdx.x;
    bool isA = (r < A_ROWS);
    int row = isA ? r : (r - A_ROWS);
    int n   = row & 15;     // spatial index i*4+j
    int bsq = row >> 4;     // b*5+s or b*15+q
    const float* src = isA ? sup : qry;
    // feature k at src[(bsq*256 + k)*16 + n]
    x[t] = src[(bsq * 256 + t) * 16 + n];
    if (t == 0) {
        x[256] = (float)(n >> 2) * 0.25f;  // coord ch0 = i/d
        x[257] = (float)(n & 3) * 0.25f;   // coord ch1 = j/d
    }
    __syncthreads();
    int koff = isA ? 0 : 258;              // sup uses W1[0:258], qry uses W1[258:516]
    float acc = isA ? gb1[t] : 0.0f;       // fold g_b1 into A side
    #pragma unroll 2
    for (int k = 0; k < 258; ++k)
        acc += x[k] * gw1[(koff + k) * 256 + t];
    float* dst = ws + (isA ? A_OFF_F : B_OFF_F) + (size_t)row * 256 + t;
    *dst = acc;
}

// ---------------- kernel 2: weights g_w2/3/4 -> bf16 fragment-linear layout ----------------
// layout: wf[((layer*16 + ntile)*8 + kk)*64 + lane][8]
//   holds W[k][n], n = ntile*16 + (lane&15), k = kk*32 + (lane>>4)*8 + j
// grid = 3*16*8 = 384 blocks, 64 threads.
__global__ void k2_wfrag(const float* __restrict__ w2, const float* __restrict__ w3,
                         const float* __restrict__ w4, unsigned short* __restrict__ wf) {
    int bid = blockIdx.x;
    int layer = bid >> 7;          // /128
    int rem = bid & 127;
    int ntile = rem >> 3;
    int kk = rem & 7;
    int l = threadIdx.x;
    const float* W = (layer == 0) ? w2 : ((layer == 1) ? w3 : w4);
    int nn = ntile * 16 + (l & 15);
    int k0 = kk * 32 + (l >> 4) * 8;
    short8 ov;
    #pragma unroll
    for (int j = 0; j < 8; ++j)
        ov[j] = (short)f2bf(W[(k0 + j) * 256 + nn]);
    *(short8*)(wf + ((size_t)bid * 64 + l) * 8) = ov;
}

// ---------------- kernel 3: g-MLP layers 2..4 + pair-sum ----------------
// grid = 600*4 blocks (bqs, 64-row tile), 256 threads (4 waves).
// waves split N: wave w owns columns [w*64, w*64+64); all 64 rows.
__launch_bounds__(256, 2)
__global__ void k3_g(const float* __restrict__ wsA, const float* __restrict__ wsB,
                     const unsigned short* __restrict__ wf,
                     const float* __restrict__ gb2, const float* __restrict__ gb3,
                     const float* __restrict__ gb4, float* __restrict__ xf) {
    __shared__ short H[2][64 * 256];   // 2 x 32KB bf16, XOR-swizzled
    int bid = blockIdx.x;
    int bqs = bid >> 2, tile = bid & 3;
    int b = bqs / 75, rem = bqs % 75, qi = rem / 5, si = rem % 5;
    int t = threadIdx.x;
    int w = t >> 6, l = t & 63;

    // ---- phase 1: H1[p,f] = relu(A[n,f] + B[m,f]), p = tile*64 + lr, m=p>>4, n=p&15
    {
        const float* Arow = wsA + ((size_t)(b * NS + si) * 16) * 256 + t;
        const float* Brow = wsB + ((size_t)(b * NQ + qi) * 16 + tile * 4) * 256 + t;
        float Av[16], Bv[4];
        #pragma unroll
        for (int n = 0; n < 16; ++n) Av[n] = Arow[n * 256];
        #pragma unroll
        for (int m = 0; m < 4; ++m) Bv[m] = Brow[m * 256];
        char* Hc = (char*)&H[0][0];
        #pragma unroll
        for (int lr = 0; lr < 64; ++lr) {
            float v = Av[lr & 15] + Bv[lr >> 4];
            v = v > 0.0f ? v : 0.0f;
            *(short*)(Hc + lr * 512 + ((2 * t) ^ ((lr & 7) << 4))) = (short)f2bf(v);
        }
    }
    __syncthreads();

    for (int L = 0; L < 3; ++L) {
        char* Hc = (char*)&H[L & 1][0];
        char* Hn = (char*)&H[(L & 1) ^ 1][0];
        const unsigned short* Wl = wf + (size_t)L * 65536;
        const float* bias = (L == 0) ? gb2 : ((L == 1) ? gb3 : gb4);
        f32x4 acc[4][4];
        #pragma unroll
        for (int mm = 0; mm < 4; ++mm)
            #pragma unroll
            for (int tt = 0; tt < 4; ++tt)
                acc[mm][tt] = (f32x4){0.f, 0.f, 0.f, 0.f};

        #pragma unroll
        for (int kk = 0; kk < 8; ++kk) {
            short8 af[4];
            #pragma unroll
            for (int mm = 0; mm < 4; ++mm) {
                int row = mm * 16 + (l & 15);
                int kbyte = kk * 64 + (l >> 4) * 16;
                af[mm] = *(const short8*)(Hc + row * 512 + (kbyte ^ ((row & 7) << 4)));
            }
            #pragma unroll
            for (int tt = 0; tt < 4; ++tt) {
                int ntile = w * 4 + tt;
                short8 bv = *(const short8*)(Wl + (((size_t)ntile * 8 + kk) * 64 + l) * 8);
                #pragma unroll
                for (int mm = 0; mm < 4; ++mm)
                    acc[mm][tt] = __builtin_amdgcn_mfma_f32_16x16x32_bf16(
                        as_bf16x8(af[mm]), as_bf16x8(bv), acc[mm][tt], 0, 0, 0);
            }
        }

        if (L < 2) {
            // epilogue: relu(acc + bias) -> Hnext (bf16, swizzled)
            #pragma unroll
            for (int tt = 0; tt < 4; ++tt) {
                int c = w * 64 + tt * 16 + (l & 15);
                float bvv = bias[c];
                #pragma unroll
                for (int mm = 0; mm < 4; ++mm) {
                    #pragma unroll
                    for (int r = 0; r < 4; ++r) {
                        int row = mm * 16 + (l >> 4) * 4 + r;
                        float v = acc[mm][tt][r] + bvv;
                        v = v > 0.0f ? v : 0.0f;
                        *(short*)(Hn + row * 512 + ((2 * c) ^ ((row & 7) << 4))) = (short)f2bf(v);
                    }
                }
            }
            __syncthreads();
        } else {
            // layer 4: relu + column-sum over the 64 rows of this block, atomicAdd to xf
            #pragma unroll
            for (int tt = 0; tt < 4; ++tt) {
                int c = w * 64 + tt * 16 + (l & 15);
                float bvv = bias[c];
                float s = 0.0f;
                #pragma unroll
                for (int mm = 0; mm < 4; ++mm)
                    #pragma unroll
                    for (int r = 0; r < 4; ++r) {
                        float v = acc[mm][tt][r] + bvv;
                        s += (v > 0.0f ? v : 0.0f);
                    }
                s += __shfl_xor(s, 16);
                s += __shfl_xor(s, 32);
                if (l < 16)
                    atomicAdd(&xf[(size_t)bqs * 256 + w * 64 + tt * 16 + l], s);
            }
        }
    }
}

// ---------------- kernel 4: f-MLP + sigmoid + MSE loss ----------------
// grid = 600 blocks, 256 threads.
__global__ void k4_f(const float* __restrict__ xf,
                     const float* __restrict__ fw1, const float* __restrict__ fb1,
                     const float* __restrict__ fw2, const float* __restrict__ fb2,
                     const float* __restrict__ fw3, const float* __restrict__ fb3,
                     const float* __restrict__ fw4, const float* __restrict__ fb4,
                     const int* __restrict__ sy, const int* __restrict__ qy,
                     float* __restrict__ out) {
    __shared__ float xb[256], yb[256], y3[32];
    int bqs = blockIdx.x;
    int b = bqs / 75, rem = bqs % 75, qi = rem / 5, si = rem % 5;
    int t = threadIdx.x;
    xb[t] = xf[(size_t)bqs * 256 + t];
    __syncthreads();
    float acc = fb1[t];
    for (int k = 0; k < 256; ++k) acc += xb[k] * fw1[k * 256 + t];
    yb[t] = acc > 0.f ? acc : 0.f;
    __syncthreads();
    acc = fb2[t];
    for (int k = 0; k < 256; ++k) acc += yb[k] * fw2[k * 256 + t];
    xb[t] = acc > 0.f ? acc : 0.f;
    __syncthreads();
    if (t < 29) {
        acc = fb3[t];
        for (int k = 0; k < 256; ++k) acc += xb[k] * fw3[k * 29 + t];
        y3[t] = acc > 0.f ? acc : 0.f;
    }
    __syncthreads();
    if (t == 0) {
        float z = fb4[0];
        for (int k = 0; k < 29; ++k) z += y3[k] * fw4[k];
        float score = 1.0f / (1.0f + __expf(-z));
        float label = (sy[b * NS + si] == qy[b * NQ + qi]) ? 1.0f : 0.0f;
        float d = label - score;
        atomicAdd(out, d * d * 0.125f);   // /b, b=8
    }
}

// ---------------- launch ----------------
extern "C" void kernel_launch(void* const* d_in, const int* in_sizes, int n_in,
                              void* d_out, int out_size, void* d_ws, size_t ws_size,
                              hipStream_t stream) {
    const float* sup = (const float*)d_in[0];
    const float* qry = (const float*)d_in[1];
    const int*   sy  = (const int*)d_in[2];
    const int*   qy  = (const int*)d_in[3];
    const float* gw1 = (const float*)d_in[4];
    const float* gb1 = (const float*)d_in[5];
    const float* gw2 = (const float*)d_in[6];
    const float* gb2 = (const float*)d_in[7];
    const float* gw3 = (const float*)d_in[8];
    const float* gb3 = (const float*)d_in[9];
    const float* gw4 = (const float*)d_in[10];
    const float* gb4 = (const float*)d_in[11];
    const float* fw1 = (const float*)d_in[12];
    const float* fb1 = (const float*)d_in[13];
    const float* fw2 = (const float*)d_in[14];
    const float* fb2 = (const float*)d_in[15];
    const float* fw3 = (const float*)d_in[16];
    const float* fb3 = (const float*)d_in[17];
    const float* fw4 = (const float*)d_in[18];
    const float* fb4 = (const float*)d_in[19];

    float* ws = (float*)d_ws;
    float* A  = ws + A_OFF_F;
    float* B  = ws + B_OFF_F;
    float* xf = ws + XF_OFF_F;
    unsigned short* wf = (unsigned short*)((char*)d_ws + WF_OFF_BYTES);
    float* out = (float*)d_out;

    hipMemsetAsync(out, 0, sizeof(float), stream);
    hipMemsetAsync(xf, 0, 600 * 256 * sizeof(float), stream);

    k1_rows<<<A_ROWS + B_ROWS, 256, 0, stream>>>(sup, qry, gw1, gb1, ws);
    k2_wfrag<<<384, 64, 0, stream>>>(gw2, gw3, gw4, wf);
    k3_g<<<600 * 4, 256, 0, stream>>>(A, B, wf, gb2, gb3, gb4, xf);
    k4_f<<<600, 256, 0, stream>>>(xf, fw1, fb1, fw2, fb2, fw3, fb3, fw4, fb4, sy, qy, out);
}